// Round 7
// baseline (291.831 us; speedup 1.0000x reference)
//
#include <hip/hip_runtime.h>

// GNN: N=50000 nodes, E=800000 edges, IN=128, HID=64, OUT=128, EH=32, 3 etypes, 2 ntypes.
//
// Strategy:
//   feat @ eW[e] = nf[src] @ eW[e][:IN] + nf[dst] @ eW[e][IN:]
//   => per-node projections P[n][192] (fp16), per-edge gather over CSR-by-dst,
//      node MLP type-partitioned. All GEMMs via MFMA bf16 3-term split (fp32 accum).
//
// R1-R7: scans, type-partition, CSR, quad layouts, proj MFMA.
// R8: aggregate LATENCY theory. R9: deg8 CSR, et in offset bits. R10: float4/8-slot.
// R11/R12: mlp2 MFMA (331->296). R13 FAILED: fp16 + 4-lane/edge -> VALU-bound.
// R14: pipelined tail (-3us) -> aggregate is beyond-L2-throughput bound.
// R15: fp16 P/h96, 8-lane/edge (286us). Profile: rank_part 47.5us leader (random
//      atomics, VALU 0.5%) — atomic/fabric latency, pipes idle.
// R16: co-schedule proj_mfma<128> WITH rank+partition in one 3-segment dispatch
//      (all three depend only on prep_all). proj's MFMA waves fill CUs while rank's
//      waves sleep on atomic latency. Dispatches 11->10.

typedef __attribute__((ext_vector_type(8))) short bf16x8_t;   // 8 bf16 in 4 VGPRs
typedef __attribute__((ext_vector_type(4))) float f32x4_t;
typedef _Float16 f16;
typedef __attribute__((ext_vector_type(4))) _Float16 f16x4_t; // 8B
typedef __attribute__((ext_vector_type(8))) _Float16 f16x8_t; // 16B

__device__ __forceinline__ void cvt_split(float x, unsigned short& h, unsigned short& l) {
  unsigned u = __float_as_uint(x);
  unsigned rh = u + 0x7FFFu + ((u >> 16) & 1u);
  h = (unsigned short)(rh >> 16);
  float xh = __uint_as_float((unsigned)h << 16);
  float xl = x - xh;
  unsigned v = __float_as_uint(xl);
  unsigned rl = v + 0x7FFFu + ((v >> 16) & 1u);
  l = (unsigned short)(rl >> 16);
}

// ---------------- W fragment prep (device body, shared by merged dispatch) ----------

template <int IN, int OUT>
__device__ __forceinline__ void prep_dev(int id,
                                         const float* __restrict__ eW,
                                         float* __restrict__ wfh,
                                         float* __restrict__ wfl,
                                         const float* __restrict__ nW,
                                         float* __restrict__ wnh,
                                         float* __restrict__ wnl) {
  constexpr int KC = IN / 32;
  constexpr int CT = OUT / 16;
  if (id < 12 * KC * 64) {
    int lane = id & 63;
    int fk = id >> 6;
    int kc = fk % KC, ct = fk / KC;
    int n = ct * 16 + (lane & 15);
    int kb = kc * 32 + ((lane >> 4) & 3) * 8;
    int half = (n >= 96) ? 1 : 0;
    int jj = n - 96 * half;
    int e = jj >> 5, o = jj & 31;
    const float* wp = eW + ((size_t)((e * 2 + half) * IN) + kb) * 32 + o;
    bf16x8_t hv, lv;
#pragma unroll
    for (int j = 0; j < 8; ++j) {
      unsigned short h, l;
      cvt_split(wp[(size_t)j * 32], h, l);
      hv[j] = (short)h;
      lv[j] = (short)l;
    }
    *(bf16x8_t*)(wfh + (size_t)id * 4) = hv;
    *(bf16x8_t*)(wfl + (size_t)id * 4) = lv;
    return;
  }
  int id2 = id - 12 * KC * 64;
  if (id2 >= 2 * CT * 3 * 64) return;
  // nW frag: B[lane][j] = nW[t][kc*32 + ((lane>>4)&3)*8 + j][ct*16 + (lane&15)]
  int lane = id2 & 63;
  int fk = id2 >> 6;
  int kc = fk % 3;
  int ct = (fk / 3) % CT;
  int t = fk / (3 * CT);
  const float* wp = nW + ((size_t)t * 96 + kc * 32 + ((lane >> 4) & 3) * 8) * OUT +
                    ct * 16 + (lane & 15);
  bf16x8_t hv, lv;
#pragma unroll
  for (int j = 0; j < 8; ++j) {
    unsigned short h, l;
    cvt_split(wp[(size_t)j * OUT], h, l);
    hv[j] = (short)h;
    lv[j] = (short)l;
  }
  *(bf16x8_t*)(wnh + (size_t)id2 * 4) = hv;
  *(bf16x8_t*)(wnl + (size_t)id2 * 4) = lv;
}

// Merged dispatch A: blocks 0-23 = eW0/nW1 frags + deg8/tcnt zero; 24-35 = eW1/nW0.
__global__ __launch_bounds__(256) void prep_all(const float* __restrict__ eW0,
                                                float* __restrict__ wf0h, float* __restrict__ wf0l,
                                                const float* __restrict__ nW1,
                                                float* __restrict__ wn1h, float* __restrict__ wn1l,
                                                const float* __restrict__ eW1,
                                                float* __restrict__ wf1h, float* __restrict__ wf1l,
                                                const float* __restrict__ nW0,
                                                float* __restrict__ wn0h, float* __restrict__ wn0l,
                                                int* __restrict__ deg8, int zn4,
                                                int* __restrict__ tcnt) {
  int bid = blockIdx.x;
  if (bid < 24) {
    int id = bid * 256 + threadIdx.x;
    int4* zb = (int4*)deg8;
    for (int z = id; z < zn4; z += 24 * 256) zb[z] = make_int4(0, 0, 0, 0);
    if (id < 2) tcnt[id] = 0;
    prep_dev<128, 128>(id, eW0, wf0h, wf0l, nW1, wn1h, wn1l);
  } else {
    int id = (bid - 24) * 256 + threadIdx.x;
    prep_dev<64, 64>(id, eW1, wf1h, wf1l, nW0, wn0h, wn0l);
  }
}

// ---------------- node projection GEMM via MFMA (device body; fp16 P output) --------

template <int IN>
__device__ __forceinline__ void proj_dev(int bid,
                                         const float* __restrict__ X,
                                         const float* __restrict__ wfh,
                                         const float* __restrict__ wfl,
                                         f16* __restrict__ P, int n) {
  constexpr int KC = IN / 32;
  __shared__ short Ah[4 * KC * 64 * 8];
  __shared__ short Al[4 * KC * 64 * 8];
  const int tx = threadIdx.x;
  const int base = bid * 64;

  for (int q = tx; q < 4 * KC * 64; q += 256) {
    int lane = q & 63;
    int fk = q >> 6;
    int kc = fk % KC, nt = fk / KC;
    int node = base + nt * 16 + (lane & 15);
    int kb = kc * 32 + ((lane >> 4) & 3) * 8;
    float xs[8];
    if (node < n) {
      float4 a = *(const float4*)(X + (size_t)node * IN + kb);
      float4 b = *(const float4*)(X + (size_t)node * IN + kb + 4);
      xs[0] = a.x; xs[1] = a.y; xs[2] = a.z; xs[3] = a.w;
      xs[4] = b.x; xs[5] = b.y; xs[6] = b.z; xs[7] = b.w;
    } else {
#pragma unroll
      for (int j = 0; j < 8; ++j) xs[j] = 0.f;
    }
    bf16x8_t hv, lv;
#pragma unroll
    for (int j = 0; j < 8; ++j) {
      unsigned short h, l;
      cvt_split(xs[j], h, l);
      hv[j] = (short)h;
      lv[j] = (short)l;
    }
    *(bf16x8_t*)(Ah + (size_t)q * 8) = hv;
    *(bf16x8_t*)(Al + (size_t)q * 8) = lv;
  }
  __syncthreads();

  const int wave = tx >> 6;
  const int lane = tx & 63;

  f32x4_t acc[4][3];
#pragma unroll
  for (int nt = 0; nt < 4; ++nt)
#pragma unroll
    for (int c = 0; c < 3; ++c) acc[nt][c] = (f32x4_t){0.f, 0.f, 0.f, 0.f};

  for (int kc = 0; kc < KC; ++kc) {
    bf16x8_t Bh[3], Bl[3];
#pragma unroll
    for (int c = 0; c < 3; ++c) {
      int ct = wave * 3 + c;
      size_t idx = ((size_t)(ct * KC + kc) * 64 + lane) * 4;
      Bh[c] = *(const bf16x8_t*)(wfh + idx);
      Bl[c] = *(const bf16x8_t*)(wfl + idx);
    }
#pragma unroll
    for (int nt = 0; nt < 4; ++nt) {
      size_t idx = ((size_t)(nt * KC + kc) * 64 + lane) * 8;
      bf16x8_t ah = *(const bf16x8_t*)(Ah + idx);
      bf16x8_t al = *(const bf16x8_t*)(Al + idx);
#pragma unroll
      for (int c = 0; c < 3; ++c) {
        acc[nt][c] = __builtin_amdgcn_mfma_f32_16x16x32_bf16(ah, Bh[c], acc[nt][c], 0, 0, 0);
        acc[nt][c] = __builtin_amdgcn_mfma_f32_16x16x32_bf16(ah, Bl[c], acc[nt][c], 0, 0, 0);
        acc[nt][c] = __builtin_amdgcn_mfma_f32_16x16x32_bf16(al, Bh[c], acc[nt][c], 0, 0, 0);
      }
    }
  }

  const int row0 = ((lane >> 4) & 3) * 4;
  const int col = lane & 15;
#pragma unroll
  for (int nt = 0; nt < 4; ++nt) {
#pragma unroll
    for (int c = 0; c < 3; ++c) {
      int jcol = (wave * 3 + c) * 16 + col;
#pragma unroll
      for (int r = 0; r < 4; ++r) {
        int node = base + nt * 16 + row0 + r;
        if (node < n) P[(size_t)node * 192 + jcol] = (f16)acc[nt][c][r];
      }
    }
  }
}

template <int IN>
__global__ __launch_bounds__(256) void proj_mfma(const float* __restrict__ X,
                                                 const float* __restrict__ wfh,
                                                 const float* __restrict__ wfl,
                                                 f16* __restrict__ P, int n) {
  proj_dev<IN>(blockIdx.x, X, wfh, wfl, P, n);
}

// ---------------- fused dispatch: proj128 (MFMA) + rank (atomics) + partition -------
// All three depend only on prep_all. proj blocks first so MFMA work is co-resident
// with rank's latency-bound atomic waves.

__global__ __launch_bounds__(256) void fused_rpp(const float* __restrict__ X,
                                                 const float* __restrict__ wfh,
                                                 const float* __restrict__ wfl,
                                                 f16* __restrict__ P, int n, int pgrid,
                                                 const int* __restrict__ dst,
                                                 int* __restrict__ deg8,
                                                 int* __restrict__ rank, int E, int egrid,
                                                 const int* __restrict__ ntype,
                                                 int* __restrict__ idxbuf,
                                                 int* __restrict__ tcnt, int ncap) {
  int bid = blockIdx.x;
  if (bid < pgrid) {
    proj_dev<128>(bid, X, wfh, wfl, P, n);
    return;
  }
  bid -= pgrid;
  if (bid < egrid) {
    int i = bid * 256 + threadIdx.x;
    if (i < E) {
      int d = dst[i];
      int r = (i >> 8) & 7;
      rank[i] = atomicAdd(&deg8[d * 8 + r], 1);
    }
    return;
  }
  bid -= egrid;
  int i = bid * 256 + threadIdx.x;
  int lane = threadIdx.x & 63;
  int t = (i < n) ? ntype[i] : -1;
  unsigned long long m0 = __ballot(t == 0);
  unsigned long long m1 = __ballot(t == 1);
  int b0 = 0, b1 = 0;
  if (lane == 0) {
    b0 = atomicAdd(&tcnt[0], (int)__popcll(m0));
    b1 = atomicAdd(&tcnt[1], (int)__popcll(m1));
  }
  b0 = __shfl(b0, 0);
  b1 = __shfl(b1, 0);
  unsigned long long below = (1ull << lane) - 1ull;
  if (t == 0) idxbuf[b0 + (int)__popcll(m0 & below)] = i;
  else if (t == 1) idxbuf[ncap + b1 + (int)__popcll(m1 & below)] = i;
}

// ---------------- scans ----------------

__global__ __launch_bounds__(256) void scan1_kernel(int* __restrict__ deg8,
                                                    int* __restrict__ rowstart,
                                                    int* __restrict__ bsum, int n) {
  __shared__ int tmp[256];
  int t = threadIdx.x;
  int base = blockIdx.x * 1024 + t * 4;
  int vdeg[4];
#pragma unroll
  for (int q = 0; q < 4; ++q) {
    int v = base + q;
    int d = 0;
    if (v < n) {
      int4 a = *(int4*)(deg8 + (size_t)v * 8);
      int4 b = *(int4*)(deg8 + (size_t)v * 8 + 4);
      int p1 = a.x, p2 = p1 + a.y, p3 = p2 + a.z, p4 = p3 + a.w;
      int p5 = p4 + b.x, p6 = p5 + b.y, p7 = p6 + b.z;
      d = p7 + b.w;
      *(int4*)(deg8 + (size_t)v * 8) = make_int4(0, p1, p2, p3);
      *(int4*)(deg8 + (size_t)v * 8 + 4) = make_int4(p4, p5, p6, p7);
    }
    vdeg[q] = d;
  }
  int s = vdeg[0] + vdeg[1] + vdeg[2] + vdeg[3];
  tmp[t] = s;
  __syncthreads();
  for (int off = 1; off < 256; off <<= 1) {
    int u = (t >= off) ? tmp[t - off] : 0;
    __syncthreads();
    tmp[t] += u;
    __syncthreads();
  }
  int excl = tmp[t] - s;
  if (base < n)     rowstart[base]     = excl;
  if (base + 1 < n) rowstart[base + 1] = excl + vdeg[0];
  if (base + 2 < n) rowstart[base + 2] = excl + vdeg[0] + vdeg[1];
  if (base + 3 < n) rowstart[base + 3] = excl + vdeg[0] + vdeg[1] + vdeg[2];
  if (t == 255) bsum[blockIdx.x] = tmp[255];
}

__global__ __launch_bounds__(64) void scan2_kernel(const int* __restrict__ bsum,
                                                   int* __restrict__ boff, int nb,
                                                   int* __restrict__ rowstart, int n) {
  int lane = threadIdx.x;
  int v = (lane < nb) ? bsum[lane] : 0;
  int incl = v;
  for (int off = 1; off < 64; off <<= 1) {
    int u = __shfl_up(incl, off, 64);
    if (lane >= off) incl += u;
  }
  if (lane < nb) boff[lane] = incl - v;
  if (lane == 63) rowstart[n] = incl;
}

// edata = byte offset src*384 + et*64 (fp16 P rows = 384B), et duplicated in low 2
// bits (chunk 64B-aligned so low 6 bits free). boff folded in here (no scan3).
__global__ __launch_bounds__(256) void fill_kernel(const int* __restrict__ src,
                                                   const int* __restrict__ dst,
                                                   const int* __restrict__ etype,
                                                   const int* __restrict__ rank,
                                                   const int* __restrict__ rowstart,
                                                   const int* __restrict__ boff,
                                                   const int* __restrict__ deg8,
                                                   int* __restrict__ edata, int E) {
  int i = blockIdx.x * 256 + threadIdx.x;
  if (i < E) {
    int d = dst[i];
    int r = (i >> 8) & 7;
    int et = etype[i];
    int pos = rowstart[d] + boff[d >> 10] + deg8[d * 8 + r] + rank[i];
    edata[pos] = src[i] * 384 + et * 65;  // et*64 + et
  }
}

// ---------------- edge aggregation (fp16, 8-lane/edge; et in edata low bits) --------
// 8 lanes/edge, each lane loads f16x4 (8B) -> edge chunk 64B; one wave VMEM inst
// covers 8 edges. 2 edges per iteration with both gathers issued before accumulation
// (2nd masked via sentinel et=3 -> no accumulator matches, addr 0 safe).

#define ACC_EDGEH(pk, v)                                              \
  {                                                                   \
    int et_ = (pk) & 3;                                               \
    bool e0_ = (et_ == 0), e1_ = (et_ == 1), e2_ = (et_ == 2);        \
    _Pragma("unroll")                                                 \
    for (int j = 0; j < 4; ++j) {                                     \
      float pb_ = e0_ ? pdb0[j] : (e1_ ? pdb1[j] : pdb2[j]);          \
      float m_ = fmaxf((float)(v)[j] + pb_, 0.f);                     \
      a0[j] += e0_ ? m_ : 0.f;                                        \
      a1[j] += e1_ ? m_ : 0.f;                                        \
      a2[j] += e2_ ? m_ : 0.f;                                        \
    }                                                                 \
    c0 += e0_; c1 += e1_;                                             \
  }

__global__ __launch_bounds__(256) void aggregate_kernel(const f16* __restrict__ P,
                                                        const int* __restrict__ rowstart,
                                                        const int* __restrict__ boff,
                                                        const int* __restrict__ edata,
                                                        const float* __restrict__ eb,
                                                        f16* __restrict__ h, int n) {
  int wid = (blockIdx.x * 256 + threadIdx.x) >> 6;
  if (wid >= n) return;
  int lane = threadIdx.x & 63;
  int co = (lane & 7) * 4;   // 4 halves per lane within the 32-col chunk
  int cb = co * 2;           // byte offset within the 64B chunk
  int slot = lane >> 3;      // 0..7 : 8 edges per wave load round
  const f16* Pd = P + (size_t)wid * 192 + 96;
  float pdb0[4], pdb1[4], pdb2[4];
  {
    f16x4_t d0 = *(const f16x4_t*)(Pd + co);
    f16x4_t d1 = *(const f16x4_t*)(Pd + 32 + co);
    f16x4_t d2 = *(const f16x4_t*)(Pd + 64 + co);
    float4 e0 = *(const float4*)(eb + co);
    float4 e1 = *(const float4*)(eb + 32 + co);
    float4 e2 = *(const float4*)(eb + 64 + co);
    pdb0[0] = (float)d0[0] + e0.x; pdb0[1] = (float)d0[1] + e0.y;
    pdb0[2] = (float)d0[2] + e0.z; pdb0[3] = (float)d0[3] + e0.w;
    pdb1[0] = (float)d1[0] + e1.x; pdb1[1] = (float)d1[1] + e1.y;
    pdb1[2] = (float)d1[2] + e1.z; pdb1[3] = (float)d1[3] + e1.w;
    pdb2[0] = (float)d2[0] + e2.x; pdb2[1] = (float)d2[1] + e2.y;
    pdb2[2] = (float)d2[2] + e2.z; pdb2[3] = (float)d2[3] + e2.w;
  }
  int s = rowstart[wid] + boff[wid >> 10];
  int e = rowstart[wid + 1] + ((wid + 1 < n) ? boff[(wid + 1) >> 10] : 0);
  const char* Pb = (const char*)P;
  float a0[4], a1[4], a2[4];
#pragma unroll
  for (int j = 0; j < 4; ++j) { a0[j] = 0.f; a1[j] = 0.f; a2[j] = 0.f; }
  int c0 = 0, c1 = 0;
  for (int i = s + slot; i < e; i += 16) {
    int p0 = edata[i];
    int p1 = 3;                     // sentinel: et bits = 3 -> accumulates nothing
    int ii = i + 8;
    if (ii < e) p1 = edata[ii];
    f16x4_t v0 = *(const f16x4_t*)(Pb + (size_t)(p0 & ~3) + cb);
    f16x4_t v1 = *(const f16x4_t*)(Pb + (size_t)(p1 & ~3) + cb);
    ACC_EDGEH(p0, v0)
    ACC_EDGEH(p1, v1)
  }
#pragma unroll
  for (int off = 8; off < 64; off <<= 1) {
#pragma unroll
    for (int j = 0; j < 4; ++j) {
      a0[j] += __shfl_xor(a0[j], off);
      a1[j] += __shfl_xor(a1[j], off);
      a2[j] += __shfl_xor(a2[j], off);
    }
    c0 += __shfl_xor(c0, off);
    c1 += __shfl_xor(c1, off);
  }
  if (slot == 0) {
    int total = e - s;
    float d0 = fmaxf((float)c0, 1.f);
    float d1 = fmaxf((float)c1, 1.f);
    float d2 = fmaxf((float)(total - c0 - c1), 1.f);
    f16* hn = h + (size_t)wid * 96;
    f16x4_t o0, o1, o2;
#pragma unroll
    for (int j = 0; j < 4; ++j) {
      o0[j] = (f16)(a0[j] / d0);
      o1[j] = (f16)(a1[j] / d1);
      o2[j] = (f16)(a2[j] / d2);
    }
    *(f16x4_t*)(hn + co)      = o0;
    *(f16x4_t*)(hn + 32 + co) = o1;
    *(f16x4_t*)(hn + 64 + co) = o2;
  }
}

// ---------------- node MLP via MFMA (type-partitioned gathered GEMM, fp16 H) --------

template <int OUT>
__global__ __launch_bounds__(256) void mlp2_mfma(const f16* __restrict__ H,
                                                 const float* __restrict__ wnh,
                                                 const float* __restrict__ wnl,
                                                 const float* __restrict__ nb,
                                                 const int* __restrict__ idxbuf,
                                                 const int* __restrict__ tcnt,
                                                 float* __restrict__ out, int ncap) {
  constexpr int CT = OUT / 16;
  constexpr int CW = CT / 4;  // col-tiles per wave
  __shared__ short Ah[12 * 64 * 8];  // [mt*3+kc][lane][8]
  __shared__ short Al[12 * 64 * 8];

  int c0 = tcnt[0];
  int nb0 = (c0 + 63) >> 6;
  int t, base, cnt;
  if ((int)blockIdx.x < nb0) {
    t = 0; base = blockIdx.x << 6; cnt = c0;
  } else {
    t = 1; base = ((int)blockIdx.x - nb0) << 6; cnt = tcnt[1];
    if (base >= cnt) return;
  }
  const int* il = idxbuf + (size_t)t * ncap;
  const float* bias = nb + t * OUT;

  const int tx = threadIdx.x;
  for (int q = tx; q < 12 * 64; q += 256) {
    int lane = q & 63;
    int fk = q >> 6;
    int kc = fk % 3, mt = fk / 3;
    int slot = base + mt * 16 + (lane & 15);
    int kb = kc * 32 + ((lane >> 4) & 3) * 8;
    float xs[8];
    if (slot < cnt) {
      int row = il[slot];
      f16x8_t a = *(const f16x8_t*)(H + (size_t)row * 96 + kb);
#pragma unroll
      for (int j = 0; j < 8; ++j) xs[j] = (float)a[j];
    } else {
#pragma unroll
      for (int j = 0; j < 8; ++j) xs[j] = 0.f;
    }
    bf16x8_t hv, lv;
#pragma unroll
    for (int j = 0; j < 8; ++j) {
      unsigned short h, l;
      cvt_split(xs[j], h, l);
      hv[j] = (short)h;
      lv[j] = (short)l;
    }
    *(bf16x8_t*)(Ah + (size_t)q * 8) = hv;
    *(bf16x8_t*)(Al + (size_t)q * 8) = lv;
  }
  __syncthreads();

  const int wave = tx >> 6;
  const int lane = tx & 63;

  f32x4_t acc[4][CW];
#pragma unroll
  for (int mt = 0; mt < 4; ++mt)
#pragma unroll
    for (int c = 0; c < CW; ++c) acc[mt][c] = (f32x4_t){0.f, 0.f, 0.f, 0.f};

  for (int kc = 0; kc < 3; ++kc) {
    bf16x8_t Bh[CW], Bl[CW];
#pragma unroll
    for (int c = 0; c < CW; ++c) {
      int ct = wave * CW + c;
      size_t idx = ((size_t)((t * CT + ct) * 3 + kc) * 64 + lane) * 4;
      Bh[c] = *(const bf16x8_t*)(wnh + idx);
      Bl[c] = *(const bf16x8_t*)(wnl + idx);
    }
#pragma unroll
    for (int mt = 0; mt < 4; ++mt) {
      size_t idx = ((size_t)((mt * 3 + kc) * 64) + lane) * 8;
      bf16x8_t ah = *(const bf16x8_t*)(Ah + idx);
      bf16x8_t al = *(const bf16x8_t*)(Al + idx);
#pragma unroll
      for (int c = 0; c < CW; ++c) {
        acc[mt][c] = __builtin_amdgcn_mfma_f32_16x16x32_bf16(ah, Bh[c], acc[mt][c], 0, 0, 0);
        acc[mt][c] = __builtin_amdgcn_mfma_f32_16x16x32_bf16(ah, Bl[c], acc[mt][c], 0, 0, 0);
        acc[mt][c] = __builtin_amdgcn_mfma_f32_16x16x32_bf16(al, Bh[c], acc[mt][c], 0, 0, 0);
      }
    }
  }

  const int row0 = ((lane >> 4) & 3) * 4;
  const int col = lane & 15;
#pragma unroll
  for (int mt = 0; mt < 4; ++mt) {
#pragma unroll
    for (int c = 0; c < CW; ++c) {
      int jcol = (wave * CW + c) * 16 + col;
      float bj = bias[jcol];
#pragma unroll
      for (int r = 0; r < 4; ++r) {
        int slot = base + mt * 16 + row0 + r;
        if (slot < cnt) {
          int row = il[slot];
          out[(size_t)row * OUT + jcol] = fmaxf(acc[mt][c][r] + bj, 0.f);
        }
      }
    }
  }
}

// ---------------- launch ----------------

extern "C" void kernel_launch(void* const* d_in, const int* in_sizes, int n_in,
                              void* d_out, int out_size, void* d_ws, size_t ws_size,
                              hipStream_t stream) {
  const float* nf    = (const float*)d_in[0];
  const int*   eidx  = (const int*)d_in[1];
  const int*   etype = (const int*)d_in[2];
  const int*   ntype = (const int*)d_in[3];
  const float* eW0   = (const float*)d_in[4];
  const float* eb0   = (const float*)d_in[5];
  const float* nW0   = (const float*)d_in[6];
  const float* nb0   = (const float*)d_in[7];
  const float* eW1   = (const float*)d_in[8];
  const float* eb1   = (const float*)d_in[9];
  const float* nW1   = (const float*)d_in[10];
  const float* nb1   = (const float*)d_in[11];
  const int N = in_sizes[3];
  const int E = in_sizes[2];
  const int* srcv = eidx;
  const int* dstv = eidx + E;

  // workspace layout: regions sized as in the fp32 layout (fp16 buffers use half of
  // their region; alignment/aliasing unchanged). rank aliases h96 region, deg8
  // aliases h64 region (CSR build completes before those are written — stream order).
  float* ws  = (float*)d_ws;
  f16*   P   = (f16*)ws;                               // region N*192 floats
  f16*   h96 = (f16*)(ws + (size_t)N * 192);           // region N*96 floats
  float* h64 = ws + (size_t)N * 192 + (size_t)N * 96;  // N*64 fp32
  int* rowstart = (int*)(h64 + (size_t)N * 64);  // N+1 (padded)
  int* tcnt     = rowstart + ((N + 4) & ~3);     // 2
  int* bsum     = tcnt + 2;                      // 64
  int* boff     = bsum + 64;                     // 64
  int* idxbuf   = boff + 64;                     // 2*N
  int* edata    = idxbuf + 2 * N;                // E
  float* wf0h   = (float*)(edata + E);           // 12288
  float* wf0l   = wf0h + 12288;                  // 12288
  float* wf1h   = wf0l + 12288;                  // 6144
  float* wf1l   = wf1h + 6144;                   // 6144
  float* wn0h   = wf1l + 6144;                   // 6144
  float* wn0l   = wn0h + 6144;                   // 6144
  float* wn1h   = wn0l + 6144;                   // 12288
  float* wn1l   = wn1h + 12288;                  // 12288
  int* rank     = (int*)(ws + (size_t)N * 192);  // E (alias of h96 region)
  int* deg8     = (int*)h64;                     // 8N (alias of h64 region)

  const int nsb = (N + 1023) / 1024;
  const int egrid = (E + 255) / 256;
  const int pargrid = (N + 255) / 256;
  const int pgrid = (N + 63) / 64;

  // A: eW0/nW1 frags + eW1/nW0 frags + deg8/tcnt zero (one dispatch).
  prep_all<<<36, 256, 0, stream>>>(eW0, wf0h, wf0l, nW1, wn1h, wn1l,
                                   eW1, wf1h, wf1l, nW0, wn0h, wn0l,
                                   deg8, N * 2, tcnt);
  // B: proj128 (MFMA) + rank (atomics) + partition co-scheduled in one dispatch.
  fused_rpp<<<pgrid + egrid + pargrid, 256, 0, stream>>>(
      nf, wf0h, wf0l, P, N, pgrid,
      dstv, deg8, rank, E, egrid,
      ntype, idxbuf, tcnt, N);
  scan1_kernel<<<nsb, 256, 0, stream>>>(deg8, rowstart, bsum, N);
  scan2_kernel<<<1, 64, 0, stream>>>(bsum, boff, nsb, rowstart, N);
  fill_kernel<<<egrid, 256, 0, stream>>>(srcv, dstv, etype, rank, rowstart, boff, deg8, edata, E);

  int agrid = (N + 3) / 4;
  int mgrid = (N + 63) / 64 + 2;

  // layer 0: 128 -> 64 (proj128 already done in fused_rpp)
  aggregate_kernel<<<agrid, 256, 0, stream>>>(P, rowstart, boff, edata, eb0, h96, N);
  mlp2_mfma<64><<<mgrid, 256, 0, stream>>>(h96, wn0h, wn0l, nb0, idxbuf, tcnt, h64, N);

  // layer 1: 64 -> 128
  proj_mfma<64><<<pgrid, 256, 0, stream>>>(h64, wf1h, wf1l, P, N);
  aggregate_kernel<<<agrid, 256, 0, stream>>>(P, rowstart, boff, edata, eb1, h96, N);
  mlp2_mfma<128><<<mgrid, 256, 0, stream>>>(h96, wn1h, wn1l, nb1, idxbuf, tcnt, (float*)d_out, N);
}

// Round 8
// 278.791 us; speedup vs baseline: 1.0468x; 1.0468x over previous
//
#include <hip/hip_runtime.h>

// GNN: N=50000 nodes, E=800000 edges, IN=128, HID=64, OUT=128, EH=32, 3 etypes, 2 ntypes.
//
// Strategy:
//   feat @ eW[e] = nf[src] @ eW[e][:IN] + nf[dst] @ eW[e][IN:]
//   => per-node projections P[n][192] (fp16), per-edge gather over CSR-by-dst,
//      node MLP type-partitioned. All GEMMs via MFMA bf16 3-term split (fp32 accum).
//
// R1-R7: scans, type-partition, CSR, quad layouts, proj MFMA.
// R8-R12: latency diagnosis, deg8 CSR, float4/8-slot agg, mlp2 MFMA (331->296).
// R13 FAILED: fp16 4-lane/edge VALU-bound. R14: pipelined tail (-3us).
// R15: fp16 P/h96 8-lane/edge (286us). rank_part 47.5us leader (fabric-bound atomics,
//      VALU 0.5% -> CUs idle).
// R16 FAILED: segmented proj|rank|partition fusion = serial sum (proj blocks launched
//      first, filled CUs, workloads time-separated, 292us).
// R17: same fusion with STRIDE-5 INTERLEAVED block mapping: proj block every 5th bid
//      -> 1-2 proj + 3-4 rank blocks per CU throughout; rank (fabric-bound) proceeds
//      at full rate while proj MFMA hides in its shadow.

typedef __attribute__((ext_vector_type(8))) short bf16x8_t;   // 8 bf16 in 4 VGPRs
typedef __attribute__((ext_vector_type(4))) float f32x4_t;
typedef _Float16 f16;
typedef __attribute__((ext_vector_type(4))) _Float16 f16x4_t; // 8B
typedef __attribute__((ext_vector_type(8))) _Float16 f16x8_t; // 16B

__device__ __forceinline__ void cvt_split(float x, unsigned short& h, unsigned short& l) {
  unsigned u = __float_as_uint(x);
  unsigned rh = u + 0x7FFFu + ((u >> 16) & 1u);
  h = (unsigned short)(rh >> 16);
  float xh = __uint_as_float((unsigned)h << 16);
  float xl = x - xh;
  unsigned v = __float_as_uint(xl);
  unsigned rl = v + 0x7FFFu + ((v >> 16) & 1u);
  l = (unsigned short)(rl >> 16);
}

// ---------------- W fragment prep (device body, shared by merged dispatch) ----------

template <int IN, int OUT>
__device__ __forceinline__ void prep_dev(int id,
                                         const float* __restrict__ eW,
                                         float* __restrict__ wfh,
                                         float* __restrict__ wfl,
                                         const float* __restrict__ nW,
                                         float* __restrict__ wnh,
                                         float* __restrict__ wnl) {
  constexpr int KC = IN / 32;
  constexpr int CT = OUT / 16;
  if (id < 12 * KC * 64) {
    int lane = id & 63;
    int fk = id >> 6;
    int kc = fk % KC, ct = fk / KC;
    int n = ct * 16 + (lane & 15);
    int kb = kc * 32 + ((lane >> 4) & 3) * 8;
    int half = (n >= 96) ? 1 : 0;
    int jj = n - 96 * half;
    int e = jj >> 5, o = jj & 31;
    const float* wp = eW + ((size_t)((e * 2 + half) * IN) + kb) * 32 + o;
    bf16x8_t hv, lv;
#pragma unroll
    for (int j = 0; j < 8; ++j) {
      unsigned short h, l;
      cvt_split(wp[(size_t)j * 32], h, l);
      hv[j] = (short)h;
      lv[j] = (short)l;
    }
    *(bf16x8_t*)(wfh + (size_t)id * 4) = hv;
    *(bf16x8_t*)(wfl + (size_t)id * 4) = lv;
    return;
  }
  int id2 = id - 12 * KC * 64;
  if (id2 >= 2 * CT * 3 * 64) return;
  // nW frag: B[lane][j] = nW[t][kc*32 + ((lane>>4)&3)*8 + j][ct*16 + (lane&15)]
  int lane = id2 & 63;
  int fk = id2 >> 6;
  int kc = fk % 3;
  int ct = (fk / 3) % CT;
  int t = fk / (3 * CT);
  const float* wp = nW + ((size_t)t * 96 + kc * 32 + ((lane >> 4) & 3) * 8) * OUT +
                    ct * 16 + (lane & 15);
  bf16x8_t hv, lv;
#pragma unroll
  for (int j = 0; j < 8; ++j) {
    unsigned short h, l;
    cvt_split(wp[(size_t)j * OUT], h, l);
    hv[j] = (short)h;
    lv[j] = (short)l;
  }
  *(bf16x8_t*)(wnh + (size_t)id2 * 4) = hv;
  *(bf16x8_t*)(wnl + (size_t)id2 * 4) = lv;
}

// Merged dispatch A: blocks 0-23 = eW0/nW1 frags + deg8/tcnt zero; 24-35 = eW1/nW0.
__global__ __launch_bounds__(256) void prep_all(const float* __restrict__ eW0,
                                                float* __restrict__ wf0h, float* __restrict__ wf0l,
                                                const float* __restrict__ nW1,
                                                float* __restrict__ wn1h, float* __restrict__ wn1l,
                                                const float* __restrict__ eW1,
                                                float* __restrict__ wf1h, float* __restrict__ wf1l,
                                                const float* __restrict__ nW0,
                                                float* __restrict__ wn0h, float* __restrict__ wn0l,
                                                int* __restrict__ deg8, int zn4,
                                                int* __restrict__ tcnt) {
  int bid = blockIdx.x;
  if (bid < 24) {
    int id = bid * 256 + threadIdx.x;
    int4* zb = (int4*)deg8;
    for (int z = id; z < zn4; z += 24 * 256) zb[z] = make_int4(0, 0, 0, 0);
    if (id < 2) tcnt[id] = 0;
    prep_dev<128, 128>(id, eW0, wf0h, wf0l, nW1, wn1h, wn1l);
  } else {
    int id = (bid - 24) * 256 + threadIdx.x;
    prep_dev<64, 64>(id, eW1, wf1h, wf1l, nW0, wn0h, wn0l);
  }
}

// ---------------- node projection GEMM via MFMA (device body; fp16 P output) --------

template <int IN>
__device__ __forceinline__ void proj_dev(int bid,
                                         const float* __restrict__ X,
                                         const float* __restrict__ wfh,
                                         const float* __restrict__ wfl,
                                         f16* __restrict__ P, int n) {
  constexpr int KC = IN / 32;
  __shared__ short Ah[4 * KC * 64 * 8];
  __shared__ short Al[4 * KC * 64 * 8];
  const int tx = threadIdx.x;
  const int base = bid * 64;

  for (int q = tx; q < 4 * KC * 64; q += 256) {
    int lane = q & 63;
    int fk = q >> 6;
    int kc = fk % KC, nt = fk / KC;
    int node = base + nt * 16 + (lane & 15);
    int kb = kc * 32 + ((lane >> 4) & 3) * 8;
    float xs[8];
    if (node < n) {
      float4 a = *(const float4*)(X + (size_t)node * IN + kb);
      float4 b = *(const float4*)(X + (size_t)node * IN + kb + 4);
      xs[0] = a.x; xs[1] = a.y; xs[2] = a.z; xs[3] = a.w;
      xs[4] = b.x; xs[5] = b.y; xs[6] = b.z; xs[7] = b.w;
    } else {
#pragma unroll
      for (int j = 0; j < 8; ++j) xs[j] = 0.f;
    }
    bf16x8_t hv, lv;
#pragma unroll
    for (int j = 0; j < 8; ++j) {
      unsigned short h, l;
      cvt_split(xs[j], h, l);
      hv[j] = (short)h;
      lv[j] = (short)l;
    }
    *(bf16x8_t*)(Ah + (size_t)q * 8) = hv;
    *(bf16x8_t*)(Al + (size_t)q * 8) = lv;
  }
  __syncthreads();

  const int wave = tx >> 6;
  const int lane = tx & 63;

  f32x4_t acc[4][3];
#pragma unroll
  for (int nt = 0; nt < 4; ++nt)
#pragma unroll
    for (int c = 0; c < 3; ++c) acc[nt][c] = (f32x4_t){0.f, 0.f, 0.f, 0.f};

  for (int kc = 0; kc < KC; ++kc) {
    bf16x8_t Bh[3], Bl[3];
#pragma unroll
    for (int c = 0; c < 3; ++c) {
      int ct = wave * 3 + c;
      size_t idx = ((size_t)(ct * KC + kc) * 64 + lane) * 4;
      Bh[c] = *(const bf16x8_t*)(wfh + idx);
      Bl[c] = *(const bf16x8_t*)(wfl + idx);
    }
#pragma unroll
    for (int nt = 0; nt < 4; ++nt) {
      size_t idx = ((size_t)(nt * KC + kc) * 64 + lane) * 8;
      bf16x8_t ah = *(const bf16x8_t*)(Ah + idx);
      bf16x8_t al = *(const bf16x8_t*)(Al + idx);
#pragma unroll
      for (int c = 0; c < 3; ++c) {
        acc[nt][c] = __builtin_amdgcn_mfma_f32_16x16x32_bf16(ah, Bh[c], acc[nt][c], 0, 0, 0);
        acc[nt][c] = __builtin_amdgcn_mfma_f32_16x16x32_bf16(ah, Bl[c], acc[nt][c], 0, 0, 0);
        acc[nt][c] = __builtin_amdgcn_mfma_f32_16x16x32_bf16(al, Bh[c], acc[nt][c], 0, 0, 0);
      }
    }
  }

  const int row0 = ((lane >> 4) & 3) * 4;
  const int col = lane & 15;
#pragma unroll
  for (int nt = 0; nt < 4; ++nt) {
#pragma unroll
    for (int c = 0; c < 3; ++c) {
      int jcol = (wave * 3 + c) * 16 + col;
#pragma unroll
      for (int r = 0; r < 4; ++r) {
        int node = base + nt * 16 + row0 + r;
        if (node < n) P[(size_t)node * 192 + jcol] = (f16)acc[nt][c][r];
      }
    }
  }
}

template <int IN>
__global__ __launch_bounds__(256) void proj_mfma(const float* __restrict__ X,
                                                 const float* __restrict__ wfh,
                                                 const float* __restrict__ wfl,
                                                 f16* __restrict__ P, int n) {
  proj_dev<IN>(blockIdx.x, X, wfh, wfl, P, n);
}

// ---------------- fused dispatch: proj128 + rank + partition, INTERLEAVED -----------
// Stride-5 mapping: bid%5==0 (and bid/5 < pgrid) -> proj block bid/5. Remaining bids
// map linearly to rank blocks then partition blocks. Keeps 1-2 proj + 3-4 rank blocks
// resident per CU for the whole dispatch: rank's fabric-bound atomics proceed at full
// rate while proj's MFMA work hides in their shadow.

__global__ __launch_bounds__(256) void fused_rpp(const float* __restrict__ X,
                                                 const float* __restrict__ wfh,
                                                 const float* __restrict__ wfl,
                                                 f16* __restrict__ P, int n, int pgrid,
                                                 const int* __restrict__ dst,
                                                 int* __restrict__ deg8,
                                                 int* __restrict__ rank, int E, int egrid,
                                                 const int* __restrict__ ntype,
                                                 int* __restrict__ idxbuf,
                                                 int* __restrict__ tcnt, int ncap) {
  int bid = blockIdx.x;
  int pb = bid / 5;
  if ((bid % 5) == 0 && pb < pgrid) {
    proj_dev<128>(pb, X, wfh, wfl, P, n);
    return;
  }
  int nproj_before = (bid % 5 == 0) ? pb : (pb + 1);
  if (nproj_before > pgrid) nproj_before = pgrid;
  int j = bid - nproj_before;
  if (j < egrid) {
    int i = j * 256 + threadIdx.x;
    if (i < E) {
      int d = dst[i];
      int r = (i >> 8) & 7;
      rank[i] = atomicAdd(&deg8[d * 8 + r], 1);
    }
    return;
  }
  j -= egrid;
  int i = j * 256 + threadIdx.x;
  int lane = threadIdx.x & 63;
  int t = (i < n) ? ntype[i] : -1;
  unsigned long long m0 = __ballot(t == 0);
  unsigned long long m1 = __ballot(t == 1);
  int b0 = 0, b1 = 0;
  if (lane == 0) {
    b0 = atomicAdd(&tcnt[0], (int)__popcll(m0));
    b1 = atomicAdd(&tcnt[1], (int)__popcll(m1));
  }
  b0 = __shfl(b0, 0);
  b1 = __shfl(b1, 0);
  unsigned long long below = (1ull << lane) - 1ull;
  if (t == 0) idxbuf[b0 + (int)__popcll(m0 & below)] = i;
  else if (t == 1) idxbuf[ncap + b1 + (int)__popcll(m1 & below)] = i;
}

// ---------------- scans ----------------

__global__ __launch_bounds__(256) void scan1_kernel(int* __restrict__ deg8,
                                                    int* __restrict__ rowstart,
                                                    int* __restrict__ bsum, int n) {
  __shared__ int tmp[256];
  int t = threadIdx.x;
  int base = blockIdx.x * 1024 + t * 4;
  int vdeg[4];
#pragma unroll
  for (int q = 0; q < 4; ++q) {
    int v = base + q;
    int d = 0;
    if (v < n) {
      int4 a = *(int4*)(deg8 + (size_t)v * 8);
      int4 b = *(int4*)(deg8 + (size_t)v * 8 + 4);
      int p1 = a.x, p2 = p1 + a.y, p3 = p2 + a.z, p4 = p3 + a.w;
      int p5 = p4 + b.x, p6 = p5 + b.y, p7 = p6 + b.z;
      d = p7 + b.w;
      *(int4*)(deg8 + (size_t)v * 8) = make_int4(0, p1, p2, p3);
      *(int4*)(deg8 + (size_t)v * 8 + 4) = make_int4(p4, p5, p6, p7);
    }
    vdeg[q] = d;
  }
  int s = vdeg[0] + vdeg[1] + vdeg[2] + vdeg[3];
  tmp[t] = s;
  __syncthreads();
  for (int off = 1; off < 256; off <<= 1) {
    int u = (t >= off) ? tmp[t - off] : 0;
    __syncthreads();
    tmp[t] += u;
    __syncthreads();
  }
  int excl = tmp[t] - s;
  if (base < n)     rowstart[base]     = excl;
  if (base + 1 < n) rowstart[base + 1] = excl + vdeg[0];
  if (base + 2 < n) rowstart[base + 2] = excl + vdeg[0] + vdeg[1];
  if (base + 3 < n) rowstart[base + 3] = excl + vdeg[0] + vdeg[1] + vdeg[2];
  if (t == 255) bsum[blockIdx.x] = tmp[255];
}

__global__ __launch_bounds__(64) void scan2_kernel(const int* __restrict__ bsum,
                                                   int* __restrict__ boff, int nb,
                                                   int* __restrict__ rowstart, int n) {
  int lane = threadIdx.x;
  int v = (lane < nb) ? bsum[lane] : 0;
  int incl = v;
  for (int off = 1; off < 64; off <<= 1) {
    int u = __shfl_up(incl, off, 64);
    if (lane >= off) incl += u;
  }
  if (lane < nb) boff[lane] = incl - v;
  if (lane == 63) rowstart[n] = incl;
}

// edata = byte offset src*384 + et*64 (fp16 P rows = 384B), et duplicated in low 2
// bits (chunk 64B-aligned so low 6 bits free). boff folded in here (no scan3).
__global__ __launch_bounds__(256) void fill_kernel(const int* __restrict__ src,
                                                   const int* __restrict__ dst,
                                                   const int* __restrict__ etype,
                                                   const int* __restrict__ rank,
                                                   const int* __restrict__ rowstart,
                                                   const int* __restrict__ boff,
                                                   const int* __restrict__ deg8,
                                                   int* __restrict__ edata, int E) {
  int i = blockIdx.x * 256 + threadIdx.x;
  if (i < E) {
    int d = dst[i];
    int r = (i >> 8) & 7;
    int et = etype[i];
    int pos = rowstart[d] + boff[d >> 10] + deg8[d * 8 + r] + rank[i];
    edata[pos] = src[i] * 384 + et * 65;  // et*64 + et
  }
}

// ---------------- edge aggregation (fp16, 8-lane/edge; et in edata low bits) --------

#define ACC_EDGEH(pk, v)                                              \
  {                                                                   \
    int et_ = (pk) & 3;                                               \
    bool e0_ = (et_ == 0), e1_ = (et_ == 1), e2_ = (et_ == 2);        \
    _Pragma("unroll")                                                 \
    for (int j = 0; j < 4; ++j) {                                     \
      float pb_ = e0_ ? pdb0[j] : (e1_ ? pdb1[j] : pdb2[j]);          \
      float m_ = fmaxf((float)(v)[j] + pb_, 0.f);                     \
      a0[j] += e0_ ? m_ : 0.f;                                        \
      a1[j] += e1_ ? m_ : 0.f;                                        \
      a2[j] += e2_ ? m_ : 0.f;                                        \
    }                                                                 \
    c0 += e0_; c1 += e1_;                                             \
  }

__global__ __launch_bounds__(256) void aggregate_kernel(const f16* __restrict__ P,
                                                        const int* __restrict__ rowstart,
                                                        const int* __restrict__ boff,
                                                        const int* __restrict__ edata,
                                                        const float* __restrict__ eb,
                                                        f16* __restrict__ h, int n) {
  int wid = (blockIdx.x * 256 + threadIdx.x) >> 6;
  if (wid >= n) return;
  int lane = threadIdx.x & 63;
  int co = (lane & 7) * 4;   // 4 halves per lane within the 32-col chunk
  int cb = co * 2;           // byte offset within the 64B chunk
  int slot = lane >> 3;      // 0..7 : 8 edges per wave load round
  const f16* Pd = P + (size_t)wid * 192 + 96;
  float pdb0[4], pdb1[4], pdb2[4];
  {
    f16x4_t d0 = *(const f16x4_t*)(Pd + co);
    f16x4_t d1 = *(const f16x4_t*)(Pd + 32 + co);
    f16x4_t d2 = *(const f16x4_t*)(Pd + 64 + co);
    float4 e0 = *(const float4*)(eb + co);
    float4 e1 = *(const float4*)(eb + 32 + co);
    float4 e2 = *(const float4*)(eb + 64 + co);
    pdb0[0] = (float)d0[0] + e0.x; pdb0[1] = (float)d0[1] + e0.y;
    pdb0[2] = (float)d0[2] + e0.z; pdb0[3] = (float)d0[3] + e0.w;
    pdb1[0] = (float)d1[0] + e1.x; pdb1[1] = (float)d1[1] + e1.y;
    pdb1[2] = (float)d1[2] + e1.z; pdb1[3] = (float)d1[3] + e1.w;
    pdb2[0] = (float)d2[0] + e2.x; pdb2[1] = (float)d2[1] + e2.y;
    pdb2[2] = (float)d2[2] + e2.z; pdb2[3] = (float)d2[3] + e2.w;
  }
  int s = rowstart[wid] + boff[wid >> 10];
  int e = rowstart[wid + 1] + ((wid + 1 < n) ? boff[(wid + 1) >> 10] : 0);
  const char* Pb = (const char*)P;
  float a0[4], a1[4], a2[4];
#pragma unroll
  for (int j = 0; j < 4; ++j) { a0[j] = 0.f; a1[j] = 0.f; a2[j] = 0.f; }
  int c0 = 0, c1 = 0;
  for (int i = s + slot; i < e; i += 16) {
    int p0 = edata[i];
    int p1 = 3;                     // sentinel: et bits = 3 -> accumulates nothing
    int ii = i + 8;
    if (ii < e) p1 = edata[ii];
    f16x4_t v0 = *(const f16x4_t*)(Pb + (size_t)(p0 & ~3) + cb);
    f16x4_t v1 = *(const f16x4_t*)(Pb + (size_t)(p1 & ~3) + cb);
    ACC_EDGEH(p0, v0)
    ACC_EDGEH(p1, v1)
  }
#pragma unroll
  for (int off = 8; off < 64; off <<= 1) {
#pragma unroll
    for (int j = 0; j < 4; ++j) {
      a0[j] += __shfl_xor(a0[j], off);
      a1[j] += __shfl_xor(a1[j], off);
      a2[j] += __shfl_xor(a2[j], off);
    }
    c0 += __shfl_xor(c0, off);
    c1 += __shfl_xor(c1, off);
  }
  if (slot == 0) {
    int total = e - s;
    float d0 = fmaxf((float)c0, 1.f);
    float d1 = fmaxf((float)c1, 1.f);
    float d2 = fmaxf((float)(total - c0 - c1), 1.f);
    f16* hn = h + (size_t)wid * 96;
    f16x4_t o0, o1, o2;
#pragma unroll
    for (int j = 0; j < 4; ++j) {
      o0[j] = (f16)(a0[j] / d0);
      o1[j] = (f16)(a1[j] / d1);
      o2[j] = (f16)(a2[j] / d2);
    }
    *(f16x4_t*)(hn + co)      = o0;
    *(f16x4_t*)(hn + 32 + co) = o1;
    *(f16x4_t*)(hn + 64 + co) = o2;
  }
}

// ---------------- node MLP via MFMA (type-partitioned gathered GEMM, fp16 H) --------

template <int OUT>
__global__ __launch_bounds__(256) void mlp2_mfma(const f16* __restrict__ H,
                                                 const float* __restrict__ wnh,
                                                 const float* __restrict__ wnl,
                                                 const float* __restrict__ nb,
                                                 const int* __restrict__ idxbuf,
                                                 const int* __restrict__ tcnt,
                                                 float* __restrict__ out, int ncap) {
  constexpr int CT = OUT / 16;
  constexpr int CW = CT / 4;  // col-tiles per wave
  __shared__ short Ah[12 * 64 * 8];  // [mt*3+kc][lane][8]
  __shared__ short Al[12 * 64 * 8];

  int c0 = tcnt[0];
  int nb0 = (c0 + 63) >> 6;
  int t, base, cnt;
  if ((int)blockIdx.x < nb0) {
    t = 0; base = blockIdx.x << 6; cnt = c0;
  } else {
    t = 1; base = ((int)blockIdx.x - nb0) << 6; cnt = tcnt[1];
    if (base >= cnt) return;
  }
  const int* il = idxbuf + (size_t)t * ncap;
  const float* bias = nb + t * OUT;

  const int tx = threadIdx.x;
  for (int q = tx; q < 12 * 64; q += 256) {
    int lane = q & 63;
    int fk = q >> 6;
    int kc = fk % 3, mt = fk / 3;
    int slot = base + mt * 16 + (lane & 15);
    int kb = kc * 32 + ((lane >> 4) & 3) * 8;
    float xs[8];
    if (slot < cnt) {
      int row = il[slot];
      f16x8_t a = *(const f16x8_t*)(H + (size_t)row * 96 + kb);
#pragma unroll
      for (int j = 0; j < 8; ++j) xs[j] = (float)a[j];
    } else {
#pragma unroll
      for (int j = 0; j < 8; ++j) xs[j] = 0.f;
    }
    bf16x8_t hv, lv;
#pragma unroll
    for (int j = 0; j < 8; ++j) {
      unsigned short h, l;
      cvt_split(xs[j], h, l);
      hv[j] = (short)h;
      lv[j] = (short)l;
    }
    *(bf16x8_t*)(Ah + (size_t)q * 8) = hv;
    *(bf16x8_t*)(Al + (size_t)q * 8) = lv;
  }
  __syncthreads();

  const int wave = tx >> 6;
  const int lane = tx & 63;

  f32x4_t acc[4][CW];
#pragma unroll
  for (int mt = 0; mt < 4; ++mt)
#pragma unroll
    for (int c = 0; c < CW; ++c) acc[mt][c] = (f32x4_t){0.f, 0.f, 0.f, 0.f};

  for (int kc = 0; kc < 3; ++kc) {
    bf16x8_t Bh[CW], Bl[CW];
#pragma unroll
    for (int c = 0; c < CW; ++c) {
      int ct = wave * CW + c;
      size_t idx = ((size_t)((t * CT + ct) * 3 + kc) * 64 + lane) * 4;
      Bh[c] = *(const bf16x8_t*)(wnh + idx);
      Bl[c] = *(const bf16x8_t*)(wnl + idx);
    }
#pragma unroll
    for (int mt = 0; mt < 4; ++mt) {
      size_t idx = ((size_t)((mt * 3 + kc) * 64) + lane) * 8;
      bf16x8_t ah = *(const bf16x8_t*)(Ah + idx);
      bf16x8_t al = *(const bf16x8_t*)(Al + idx);
#pragma unroll
      for (int c = 0; c < CW; ++c) {
        acc[mt][c] = __builtin_amdgcn_mfma_f32_16x16x32_bf16(ah, Bh[c], acc[mt][c], 0, 0, 0);
        acc[mt][c] = __builtin_amdgcn_mfma_f32_16x16x32_bf16(ah, Bl[c], acc[mt][c], 0, 0, 0);
        acc[mt][c] = __builtin_amdgcn_mfma_f32_16x16x32_bf16(al, Bh[c], acc[mt][c], 0, 0, 0);
      }
    }
  }

  const int row0 = ((lane >> 4) & 3) * 4;
  const int col = lane & 15;
#pragma unroll
  for (int mt = 0; mt < 4; ++mt) {
#pragma unroll
    for (int c = 0; c < CW; ++c) {
      int jcol = (wave * CW + c) * 16 + col;
      float bj = bias[jcol];
#pragma unroll
      for (int r = 0; r < 4; ++r) {
        int slot = base + mt * 16 + row0 + r;
        if (slot < cnt) {
          int row = il[slot];
          out[(size_t)row * OUT + jcol] = fmaxf(acc[mt][c][r] + bj, 0.f);
        }
      }
    }
  }
}

// ---------------- launch ----------------

extern "C" void kernel_launch(void* const* d_in, const int* in_sizes, int n_in,
                              void* d_out, int out_size, void* d_ws, size_t ws_size,
                              hipStream_t stream) {
  const float* nf    = (const float*)d_in[0];
  const int*   eidx  = (const int*)d_in[1];
  const int*   etype = (const int*)d_in[2];
  const int*   ntype = (const int*)d_in[3];
  const float* eW0   = (const float*)d_in[4];
  const float* eb0   = (const float*)d_in[5];
  const float* nW0   = (const float*)d_in[6];
  const float* nb0   = (const float*)d_in[7];
  const float* eW1   = (const float*)d_in[8];
  const float* eb1   = (const float*)d_in[9];
  const float* nW1   = (const float*)d_in[10];
  const float* nb1   = (const float*)d_in[11];
  const int N = in_sizes[3];
  const int E = in_sizes[2];
  const int* srcv = eidx;
  const int* dstv = eidx + E;

  // workspace layout: regions sized as in the fp32 layout (fp16 buffers use half of
  // their region; alignment/aliasing unchanged). rank aliases h96 region, deg8
  // aliases h64 region (CSR build completes before those are written — stream order).
  float* ws  = (float*)d_ws;
  f16*   P   = (f16*)ws;                               // region N*192 floats
  f16*   h96 = (f16*)(ws + (size_t)N * 192);           // region N*96 floats
  float* h64 = ws + (size_t)N * 192 + (size_t)N * 96;  // N*64 fp32
  int* rowstart = (int*)(h64 + (size_t)N * 64);  // N+1 (padded)
  int* tcnt     = rowstart + ((N + 4) & ~3);     // 2
  int* bsum     = tcnt + 2;                      // 64
  int* boff     = bsum + 64;                     // 64
  int* idxbuf   = boff + 64;                     // 2*N
  int* edata    = idxbuf + 2 * N;                // E
  float* wf0h   = (float*)(edata + E);           // 12288
  float* wf0l   = wf0h + 12288;                  // 12288
  float* wf1h   = wf0l + 12288;                  // 6144
  float* wf1l   = wf1h + 6144;                   // 6144
  float* wn0h   = wf1l + 6144;                   // 6144
  float* wn0l   = wn0h + 6144;                   // 6144
  float* wn1h   = wn0l + 6144;                   // 12288
  float* wn1l   = wn1h + 12288;                  // 12288
  int* rank     = (int*)(ws + (size_t)N * 192);  // E (alias of h96 region)
  int* deg8     = (int*)h64;                     // 8N (alias of h64 region)

  const int nsb = (N + 1023) / 1024;
  const int egrid = (E + 255) / 256;
  const int pargrid = (N + 255) / 256;
  const int pgrid = (N + 63) / 64;

  // A: eW0/nW1 frags + eW1/nW0 frags + deg8/tcnt zero (one dispatch).
  prep_all<<<36, 256, 0, stream>>>(eW0, wf0h, wf0l, nW1, wn1h, wn1l,
                                   eW1, wf1h, wf1l, nW0, wn0h, wn0l,
                                   deg8, N * 2, tcnt);
  // B: proj128 + rank + partition, stride-5 interleaved co-schedule.
  fused_rpp<<<pgrid + egrid + pargrid, 256, 0, stream>>>(
      nf, wf0h, wf0l, P, N, pgrid,
      dstv, deg8, rank, E, egrid,
      ntype, idxbuf, tcnt, N);
  scan1_kernel<<<nsb, 256, 0, stream>>>(deg8, rowstart, bsum, N);
  scan2_kernel<<<1, 64, 0, stream>>>(bsum, boff, nsb, rowstart, N);
  fill_kernel<<<egrid, 256, 0, stream>>>(srcv, dstv, etype, rank, rowstart, boff, deg8, edata, E);

  int agrid = (N + 3) / 4;
  int mgrid = (N + 63) / 64 + 2;

  // layer 0: 128 -> 64 (proj128 already done in fused_rpp)
  aggregate_kernel<<<agrid, 256, 0, stream>>>(P, rowstart, boff, edata, eb0, h96, N);
  mlp2_mfma<64><<<mgrid, 256, 0, stream>>>(h96, wn0h, wn0l, nb0, idxbuf, tcnt, h64, N);

  // layer 1: 64 -> 128
  proj_mfma<64><<<pgrid, 256, 0, stream>>>(h64, wf1h, wf1l, P, N);
  aggregate_kernel<<<agrid, 256, 0, stream>>>(P, rowstart, boff, edata, eb1, h96, N);
  mlp2_mfma<128><<<mgrid, 256, 0, stream>>>(h96, wn1h, wn1l, nb1, idxbuf, tcnt, (float*)d_out, N);
}